// Round 1
// baseline (847.677 us; speedup 1.0000x reference)
//
#include <hip/hip_runtime.h>
#include <math.h>

#define EMB_D 64
#define N_EMB_K 1024
#define HW 4096        // 64*64
#define CHW 262144     // 64*4096
#define NPTS 65536     // 16*64*64
#define Q_OFF 1
#define PERP_OFF 4194305
#define ENC_OFF 4194306

// ws layout (floats): [0..1023] c[k]=0.5*||W_k||^2 ; [1024..2047] hist (uint) ; [2048] loss accum

__global__ __launch_bounds__(256) void vq_prep(const float* __restrict__ W,
                                               float* __restrict__ ws) {
    int k = blockIdx.x * 256 + threadIdx.x;
    if (k < N_EMB_K) {
        const float* wk = W + (k << 6);
        float s = 0.f;
        #pragma unroll
        for (int d = 0; d < EMB_D; ++d) s = fmaf(wk[d], wk[d], s);
        ws[k] = 0.5f * s;
        ((unsigned int*)ws)[1024 + k] = 0u;
        if (k == 0) ws[2048] = 0.f;
    }
}

__global__ __launch_bounds__(256, 4) void vq_main(const float* __restrict__ in,
                                                  const float* __restrict__ W,
                                                  float* __restrict__ out,
                                                  float* __restrict__ ws) {
    __shared__ float s_best[4][64];
    __shared__ int   s_bidx[4][64];
    __shared__ float s_xsq[64];
    __shared__ int   s_bk[64];

    const int tid   = threadIdx.x;
    const int p     = tid & 63;        // point within block
    const int slice = tid >> 6;        // k-slice (wave-uniform)
    const int n  = blockIdx.x * 64 + p;
    const int b  = n >> 12;
    const int hw = n & 4095;
    const float* xp = in + b * CHW + hw;

    float x[EMB_D];
    #pragma unroll
    for (int d = 0; d < EMB_D; ++d) x[d] = xp[d * HW];

    if (slice == 0) {
        float sq = 0.f;
        #pragma unroll
        for (int d = 0; d < EMB_D; ++d) sq = fmaf(x[d], x[d], sq);
        s_xsq[p] = sq;
    }

    const float* c = ws;
    const int k0 = slice << 8;
    float best = -3.0e38f;
    int   bk   = k0;
    #pragma unroll 2
    for (int k = k0; k < k0 + 256; ++k) {
        const float4* wk = (const float4*)(W + (k << 6));
        float s0 = 0.f, s1 = 0.f, s2 = 0.f, s3 = 0.f;
        #pragma unroll
        for (int d4 = 0; d4 < 16; ++d4) {
            float4 wv = wk[d4];
            s0 = fmaf(x[d4 * 4 + 0], wv.x, s0);
            s1 = fmaf(x[d4 * 4 + 1], wv.y, s1);
            s2 = fmaf(x[d4 * 4 + 2], wv.z, s2);
            s3 = fmaf(x[d4 * 4 + 3], wv.w, s3);
        }
        float s = ((s0 + s1) + (s2 + s3)) - c[k];
        if (s > best) { best = s; bk = k; }   // strict > keeps lowest k on ties
    }
    s_best[slice][p] = best;
    s_bidx[slice][p] = bk;
    __syncthreads();

    if (tid < 64) {
        float bb = s_best[0][tid];
        int   bi = s_bidx[0][tid];
        #pragma unroll
        for (int sl = 1; sl < 4; ++sl) {
            float v = s_best[sl][tid];
            if (v > bb) { bb = v; bi = s_bidx[sl][tid]; }  // ascending k-slices: strict > = first-min
        }
        s_bk[tid] = bi;
        atomicAdd((unsigned int*)ws + 1024 + bi, 1u);
        float dist = s_xsq[tid] - 2.0f * bb;   // ||x-w||^2 of the winner
        #pragma unroll
        for (int off = 32; off > 0; off >>= 1)
            dist += __shfl_xor(dist, off, 64);
        if (tid == 0) atomicAdd(ws + 2048, dist);
    }
    __syncthreads();

    // ---- encodings: 64 rows x 1024 one-hot floats, coalesced float2 stores
    float* enc = out + ENC_OFF;   // byte offset = 8 mod 16 -> only 8B-aligned
    const int cbase = tid << 2;
    for (int r = 0; r < 64; ++r) {
        const int bkr = s_bk[r];
        const size_t row = ((size_t)(blockIdx.x * 64 + r)) << 10;
        float2 v0, v1;
        v0.x = (bkr == cbase + 0) ? 1.0f : 0.0f;
        v0.y = (bkr == cbase + 1) ? 1.0f : 0.0f;
        v1.x = (bkr == cbase + 2) ? 1.0f : 0.0f;
        v1.y = (bkr == cbase + 3) ? 1.0f : 0.0f;
        float2* dst = (float2*)(enc + row + cbase);
        dst[0] = v0;
        dst[1] = v1;
    }

    // ---- quantized_st in NCHW: out[1 + b*CHW + d*HW + hw] = x + (q - x)
    {
        float* quant = out + Q_OFF;
        const float* wrow = W + (s_bk[p] << 6);
        #pragma unroll
        for (int dd = 0; dd < 16; ++dd) {
            const int d = (slice << 4) + dd;
            const int idx = b * CHW + d * HW + hw;
            const float xv = in[idx];
            quant[idx] = xv + (wrow[d] - xv);   // straight-through arithmetic, bit-matching ref
        }
    }
}

__global__ __launch_bounds__(256) void vq_final(const float* __restrict__ ws,
                                                float* __restrict__ out) {
    __shared__ float red[256];
    const int tid = threadIdx.x;
    const unsigned int* hist = (const unsigned int*)ws + 1024;
    float local = 0.f;
    #pragma unroll
    for (int j = 0; j < 4; ++j) {
        const unsigned int cnt = hist[tid + j * 256];
        const float pr = (float)cnt * (1.0f / 65536.0f);
        local += pr * logf(pr + 1e-10f);
    }
    red[tid] = local;
    __syncthreads();
    for (int off = 128; off > 0; off >>= 1) {
        if (tid < off) red[tid] += red[tid + off];
        __syncthreads();
    }
    if (tid == 0) {
        out[PERP_OFF] = expf(-red[0]);
        out[0] = 1.25f * ws[2048] * (1.0f / 4194304.0f);
    }
}

extern "C" void kernel_launch(void* const* d_in, const int* in_sizes, int n_in,
                              void* d_out, int out_size, void* d_ws, size_t ws_size,
                              hipStream_t stream) {
    const float* in = (const float*)d_in[0];   // (16,64,64,64) fp32 NCHW
    const float* W  = (const float*)d_in[1];   // (1024,64) fp32
    float* out = (float*)d_out;                // [loss(1) | quant(4194304) | perp(1) | enc(67108864)]
    float* ws  = (float*)d_ws;

    vq_prep<<<4, 256, 0, stream>>>(W, ws);
    vq_main<<<NPTS / 64, 256, 0, stream>>>(in, W, out, ws);
    vq_final<<<1, 256, 0, stream>>>(ws, out);
}

// Round 3
// 376.461 us; speedup vs baseline: 2.2517x; 2.2517x over previous
//
#include <hip/hip_runtime.h>
#include <math.h>

#define EMB_D 64
#define N_EMB_K 1024
#define HW 4096        // 64*64
#define CHW 262144     // 64*4096
#define NPTS 65536     // 16*64*64
#define Q_OFF 1
#define PERP_OFF 4194305
#define ENC_OFF 4194306

// ws layout (floats): [0..1023] c[k]=0.5*||W_k||^2 ; [1024..2047] hist (uint) ; [2048] loss accum

typedef __attribute__((ext_vector_type(8))) short short8;   // 8 bf16 = 4 VGPRs (MFMA A/B frag)
typedef __attribute__((ext_vector_type(4))) float float4v;  // MFMA C/D frag
typedef __attribute__((ext_vector_type(2))) float f2;       // native float2 (nontemporal-compatible)

union S8 { short8 v; unsigned short u[8]; };

__device__ __forceinline__ unsigned short f2bf_rne(float f) {
    unsigned u = __builtin_bit_cast(unsigned, f);
    unsigned r = u + 0x7FFFu + ((u >> 16) & 1u);
    return (unsigned short)(r >> 16);
}
__device__ __forceinline__ float bf2f(unsigned short h) {
    unsigned u = ((unsigned)h) << 16;
    return __builtin_bit_cast(float, u);
}

__global__ __launch_bounds__(256) void vq_prep(const float* __restrict__ W,
                                               float* __restrict__ ws) {
    int k = blockIdx.x * 256 + threadIdx.x;
    if (k < N_EMB_K) {
        const float* wk = W + (k << 6);
        float s = 0.f;
        #pragma unroll
        for (int d = 0; d < EMB_D; ++d) s = fmaf(wk[d], wk[d], s);
        ws[k] = 0.5f * s;
        ((unsigned int*)ws)[1024 + k] = 0u;
        if (k == 0) ws[2048] = 0.f;
    }
}

__global__ __launch_bounds__(256, 4) void vq_main(const float* __restrict__ in,
                                                  const float* __restrict__ W,
                                                  float* __restrict__ out,
                                                  float* __restrict__ ws) {
    __shared__ float  x_lds[64 * 64];             // [d][p] fp32, 16 KB
    __shared__ short8 w_frag[4][2][2][64];        // [sub][kstep][hi/lo][lane], 16 KB
    __shared__ int    s_bk[64];

    const int tid  = threadIdx.x;
    const int lane = tid & 63;
    const int wv   = tid >> 6;      // wave id, owns points wv*16..wv*16+15
    const int n16  = lane & 15;     // MFMA col (code-in-tile)
    const int quad = lane >> 4;

    const int blk = blockIdx.x;
    const int b   = blk >> 6;               // batch index (64 blocks per batch image)
    const int hw0 = (blk & 63) * 64;        // 64 consecutive hw positions

    // ---- stage x tile (64 d x 64 points) into LDS, coalesced over hw ----
    {
        const float* src = in + (size_t)b * CHW + hw0;
        #pragma unroll
        for (int i = 0; i < 16; ++i) {
            const int d = wv * 16 + i;
            x_lds[d * 64 + lane] = src[d * HW + lane];
        }
    }
    __syncthreads();

    // ---- build A fragments (hi/lo split) for this wave's 16 points ----
    // A layout (16x16x32): m = lane&15, k = quad*8 + j  [m120-verified]
    short8 ah0, al0, ah1, al1;
    {
        const int p = wv * 16 + n16;
        S8 h0, l0, h1, l1;
        #pragma unroll
        for (int j = 0; j < 8; ++j) {
            const float v0 = x_lds[(quad * 8 + j) * 64 + p];
            const float v1 = x_lds[(32 + quad * 8 + j) * 64 + p];
            h0.u[j] = f2bf_rne(v0);
            l0.u[j] = f2bf_rne(v0 - bf2f(h0.u[j]));
            h1.u[j] = f2bf_rne(v1);
            l1.u[j] = f2bf_rne(v1 - bf2f(h1.u[j]));
        }
        ah0 = h0.v; al0 = l0.v; ah1 = h1.v; al1 = l1.v;
    }

    float bestv[4] = {-3.0e38f, -3.0e38f, -3.0e38f, -3.0e38f};
    int   bestk[4] = {0, 0, 0, 0};
    const float* cvec = ws;   // 0.5*||w_k||^2

    for (int round = 0; round < 16; ++round) {
        if (round) __syncthreads();
        // ---- stage 64 codes into LDS as pre-swizzled hi/lo B-fragments ----
        #pragma unroll
        for (int t = 0; t < 2; ++t) {
            const int ch   = tid + t * 256;      // 512 fragment chunks per round
            const int sub  = ch >> 7;
            const int ks   = (ch >> 6) & 1;
            const int l6   = ch & 63;
            const int code = round * 64 + sub * 16 + (l6 & 15);
            const int d0   = ks * 32 + (l6 >> 4) * 8;
            const float4* wp = (const float4*)(W + code * 64 + d0);
            const float4 f0 = wp[0], f1 = wp[1];
            const float vv[8] = {f0.x, f0.y, f0.z, f0.w, f1.x, f1.y, f1.z, f1.w};
            S8 hs, ls;
            #pragma unroll
            for (int j = 0; j < 8; ++j) {
                hs.u[j] = f2bf_rne(vv[j]);
                ls.u[j] = f2bf_rne(vv[j] - bf2f(hs.u[j]));
            }
            w_frag[sub][ks][0][l6] = hs.v;
            w_frag[sub][ks][1][l6] = ls.v;
        }
        __syncthreads();

        // ---- 4 sub-tiles of 16 codes: 6 MFMAs each (hi*hi + lo*hi + hi*lo) ----
        #pragma unroll
        for (int sub = 0; sub < 4; ++sub) {
            const int code = round * 64 + sub * 16 + n16;
            const float cv = cvec[code];
            const short8 bh0 = w_frag[sub][0][0][lane];
            const short8 bl0 = w_frag[sub][0][1][lane];
            const short8 bh1 = w_frag[sub][1][0][lane];
            const short8 bl1 = w_frag[sub][1][1][lane];
            float4v acc = {0.f, 0.f, 0.f, 0.f};
            acc = __builtin_amdgcn_mfma_f32_16x16x32_bf16(ah0, bh0, acc, 0, 0, 0);
            acc = __builtin_amdgcn_mfma_f32_16x16x32_bf16(ah1, bh1, acc, 0, 0, 0);
            acc = __builtin_amdgcn_mfma_f32_16x16x32_bf16(al0, bh0, acc, 0, 0, 0);
            acc = __builtin_amdgcn_mfma_f32_16x16x32_bf16(al1, bh1, acc, 0, 0, 0);
            acc = __builtin_amdgcn_mfma_f32_16x16x32_bf16(ah0, bl0, acc, 0, 0, 0);
            acc = __builtin_amdgcn_mfma_f32_16x16x32_bf16(ah1, bl1, acc, 0, 0, 0);
            // C layout: col = lane&15 (code), row = quad*4 + r (point) [m89-verified]
            #pragma unroll
            for (int r = 0; r < 4; ++r) {
                const float s = acc[r] - cv;
                if (s > bestv[r]) { bestv[r] = s; bestk[r] = code; }  // strict > => lowest k on tie
            }
        }
    }

    // ---- cross-lane argmax reduce within each 16-lane col group ----
    #pragma unroll
    for (int off = 1; off < 16; off <<= 1) {
        #pragma unroll
        for (int r = 0; r < 4; ++r) {
            const float ov = __shfl_xor(bestv[r], off, 64);
            const int   oi = __shfl_xor(bestk[r], off, 64);
            if (ov > bestv[r] || (ov == bestv[r] && oi < bestk[r])) {
                bestv[r] = ov; bestk[r] = oi;
            }
        }
    }
    if (n16 == 0) {
        #pragma unroll
        for (int r = 0; r < 4; ++r) s_bk[wv * 16 + quad * 4 + r] = bestk[r];
    }
    __syncthreads();

    if (tid < 64) atomicAdd((unsigned int*)ws + 1024 + s_bk[tid], 1u);

    // ---- quantized_st (NCHW) + exact fp32 loss from winner rows ----
    {
        float* quant = out + Q_OFF;
        const int p  = lane;
        const int bk = s_bk[p];
        const float* wrow = W + (bk << 6);
        float lsum = 0.f;
        #pragma unroll
        for (int dd = 0; dd < 16; ++dd) {
            const int d = wv * 16 + dd;
            const float xv  = x_lds[d * 64 + p];
            const float qv  = wrow[d];
            const float diff = qv - xv;
            lsum = fmaf(diff, diff, lsum);
            __builtin_nontemporal_store(xv + diff,
                quant + (size_t)b * CHW + d * HW + hw0 + p);
        }
        #pragma unroll
        for (int off = 1; off < 64; off <<= 1) lsum += __shfl_xor(lsum, off, 64);
        if (lane == 0) atomicAdd(ws + 2048, lsum);
    }

    // ---- encodings: 64 rows x 1024 one-hot, dense f2 streaming stores ----
    {
        f2* enc2 = (f2*)(out + ENC_OFF);   // base is 8B-aligned
        const size_t rowbase = (size_t)blk * 64 * 512;
        const int c0 = 2 * tid;          // cols (c0, c0+1)
        const int c1 = 2 * tid + 512;    // cols (c1, c1+1)
        for (int r = 0; r < 64; ++r) {
            const int bkr = s_bk[r];
            f2 v0, v1;
            v0.x = (bkr == c0)     ? 1.0f : 0.0f;
            v0.y = (bkr == c0 + 1) ? 1.0f : 0.0f;
            v1.x = (bkr == c1)     ? 1.0f : 0.0f;
            v1.y = (bkr == c1 + 1) ? 1.0f : 0.0f;
            const size_t rb = rowbase + (size_t)r * 512;
            __builtin_nontemporal_store(v0, enc2 + rb + tid);
            __builtin_nontemporal_store(v1, enc2 + rb + tid + 256);
        }
    }
}

__global__ __launch_bounds__(256) void vq_final(const float* __restrict__ ws,
                                                float* __restrict__ out) {
    __shared__ float red[256];
    const int tid = threadIdx.x;
    const unsigned int* hist = (const unsigned int*)ws + 1024;
    float local = 0.f;
    #pragma unroll
    for (int j = 0; j < 4; ++j) {
        const unsigned int cnt = hist[tid + j * 256];
        const float pr = (float)cnt * (1.0f / 65536.0f);
        local += pr * logf(pr + 1e-10f);
    }
    red[tid] = local;
    __syncthreads();
    for (int off = 128; off > 0; off >>= 1) {
        if (tid < off) red[tid] += red[tid + off];
        __syncthreads();
    }
    if (tid == 0) {
        out[PERP_OFF] = expf(-red[0]);
        out[0] = 1.25f * ws[2048] * (1.0f / 4194304.0f);
    }
}

extern "C" void kernel_launch(void* const* d_in, const int* in_sizes, int n_in,
                              void* d_out, int out_size, void* d_ws, size_t ws_size,
                              hipStream_t stream) {
    const float* in = (const float*)d_in[0];   // (16,64,64,64) fp32 NCHW
    const float* W  = (const float*)d_in[1];   // (1024,64) fp32
    float* out = (float*)d_out;                // [loss(1) | quant(4194304) | perp(1) | enc(67108864)]
    float* ws  = (float*)d_ws;

    vq_prep<<<4, 256, 0, stream>>>(W, ws);
    vq_main<<<NPTS / 64, 256, 0, stream>>>(in, W, out, ws);
    vq_final<<<1, 256, 0, stream>>>(ws, out);
}